// Round 4
// baseline (620.434 us; speedup 1.0000x reference)
//
#include <hip/hip_runtime.h>

#define NN 32      // nodes
#define FF 64      // GAT out features
#define HH 128     // LSTM hidden
#define G4 512     // 4*H
#define BB 32      // batch
#define TT 512     // time steps
#define ET 128     // 96 edges + 32 self loops
#define NPOS (BB*TT)

__device__ __forceinline__ float frcp(float x) { return __builtin_amdgcn_rcpf(x); }
__device__ __forceinline__ float sigm(float x) { return frcp(1.f + __expf(-x)); }
__device__ __forceinline__ float tanh_fast(float x) { return 1.f - 2.f * frcp(1.f + __expf(2.f * x)); }

// raw barrier: LDS drain only — does NOT drain vmcnt, so global prefetches
// issued before it stay in flight (unlike __syncthreads, which drains vmcnt(0))
#define LDS_BARRIER() asm volatile("s_waitcnt lgkmcnt(0)\n\ts_barrier" ::: "memory")

// ---------------- prep: fold GAT linear into LSTM input weights ----------------
__global__ __launch_bounds__(512) void prep_kernel(const float* __restrict__ w_gat,
                                                   const float* __restrict__ b_gat,
                                                   const float* __restrict__ W_ih,
                                                   float* __restrict__ W_eff,
                                                   float* __restrict__ biasp) {
  int j = threadIdx.x;
  int n = blockIdx.x;
  float accw = 0.f, accb = 0.f;
#pragma unroll 8
  for (int f = 0; f < FF; ++f) {
    float wv = W_ih[(n * FF + f) * G4 + j];
    accw = fmaf(w_gat[f], wv, accw);
    accb = fmaf(b_gat[f], wv, accb);
  }
  W_eff[n * G4 + j] = accw;
  biasp[n * G4 + j] = accb;
}

__global__ __launch_bounds__(512) void prep2_kernel(const float* __restrict__ biasp,
                                                    const float* __restrict__ b_ih,
                                                    const float* __restrict__ b_hh,
                                                    const float* __restrict__ w_gat,
                                                    const float* __restrict__ att_src,
                                                    const float* __restrict__ att_dst,
                                                    float* __restrict__ bias_eff,
                                                    float* __restrict__ scal) {
  int j = threadIdx.x;
  float acc = b_ih[j] + b_hh[j];
#pragma unroll
  for (int n = 0; n < NN; ++n) acc += biasp[n * G4 + j];
  bias_eff[j] = acc;
  if (j == 0) {
    float cs = 0.f, cd = 0.f;
    for (int f = 0; f < FF; ++f) {
      cs = fmaf(w_gat[f], att_src[f], cs);
      cd = fmaf(w_gat[f], att_dst[f], cd);
    }
    scal[0] = cs;
    scal[1] = cd;
  }
}

// ---------------- fused GAT + xw: 8 positions per 256-thread block ----------------
__global__ __launch_bounds__(256) void gatxw_kernel(const float* __restrict__ x_seq,
                                                    const int* __restrict__ ei,
                                                    const float* __restrict__ scal,
                                                    const float* __restrict__ W_eff,
                                                    const float* __restrict__ bias_eff,
                                                    float* __restrict__ xw) {
  __shared__ int ep[ET];
  __shared__ float xs[8 * 32];
  __shared__ float sl[8 * 32];
  int tid = threadIdx.x;
  int posbase = blockIdx.x * 8;
  float we0[NN], we1[NN];
#pragma unroll
  for (int nn = 0; nn < NN; ++nn) {
    we0[nn] = W_eff[nn * G4 + tid];
    we1[nn] = W_eff[nn * G4 + 256 + tid];
  }
  float b0 = bias_eff[tid], b1 = bias_eff[256 + tid];
  if (tid < ET) {
    int s, d;
    if (tid < 96) { s = ei[tid]; d = ei[96 + tid]; }
    else { s = tid - 96; d = tid - 96; }
    ep[tid] = s | (d << 16);
  }
  int p = tid >> 5, n = tid & 31;
  xs[tid] = x_seq[posbase * NN + tid];  // coalesced
  __syncthreads();
  float cs = scal[0], cd = scal[1];
  int base = p * 32;
  float m = -3.0e38f;
  for (int e = 0; e < ET; ++e) {
    int pe = ep[e];
    int se = pe & 0xffff, de = pe >> 16;
    float ev = cs * xs[base + se] + cd * xs[base + de];
    ev = ev > 0.f ? ev : 0.2f * ev;  // LeakyReLU(0.2)
    if (de == n) m = fmaxf(m, ev);
  }
  float z = 0.f, sa = 0.f;
  for (int e = 0; e < ET; ++e) {
    int pe = ep[e];
    int se = pe & 0xffff, de = pe >> 16;
    float xsv = xs[base + se];
    float ev = cs * xsv + cd * xs[base + de];
    ev = ev > 0.f ? ev : 0.2f * ev;
    float ex = __expf(ev - m);
    float exm = (de == n) ? ex : 0.f;
    z += exm;
    sa = fmaf(exm, xsv, sa);
  }
  sl[p * 32 + n] = sa * frcp(z);
  __syncthreads();
  for (int pp = 0; pp < 8; ++pp) {
    const float4* sp = (const float4*)&sl[pp * 32];
    float a0 = b0, a1 = b1;
#pragma unroll
    for (int q = 0; q < 8; ++q) {
      float4 sv = sp[q];
      a0 = fmaf(sv.x, we0[4 * q], a0);
      a0 = fmaf(sv.y, we0[4 * q + 1], a0);
      a0 = fmaf(sv.z, we0[4 * q + 2], a0);
      a0 = fmaf(sv.w, we0[4 * q + 3], a0);
      a1 = fmaf(sv.x, we1[4 * q], a1);
      a1 = fmaf(sv.y, we1[4 * q + 1], a1);
      a1 = fmaf(sv.z, we1[4 * q + 2], a1);
      a1 = fmaf(sv.w, we1[4 * q + 3], a1);
    }
    size_t row = (size_t)(posbase + pp) * G4;
    xw[row + tid] = a0;
    xw[row + 256 + tid] = a1;
  }
}

// ---------------- LSTM scan: one block per batch, thread j owns gate column j ----------
// R1/R3 failure mode: `float w[128]` alloca never SROA-promoted -> scratch
// re-reads every step -> L2-BW bound (~256KB/step/CU ~ 1900 cyc/step).
// Fix: 32 NAMED float4s via X-macro (SSA by construction, no alloca), and
// __launch_bounds__(512,1) so the 512-reg budget removes any spill motive.

#define ALL_Q(X) \
  X(0,a0) X(1,a1) X(2,a2) X(3,a3) X(4,a0) X(5,a1) X(6,a2) X(7,a3) \
  X(8,a0) X(9,a1) X(10,a2) X(11,a3) X(12,a0) X(13,a1) X(14,a2) X(15,a3) \
  X(16,a0) X(17,a1) X(18,a2) X(19,a3) X(20,a0) X(21,a1) X(22,a2) X(23,a3) \
  X(24,a0) X(25,a1) X(26,a2) X(27,a3) X(28,a0) X(29,a1) X(30,a2) X(31,a3)

#define DECLW(q, a) float4 w##q = make_float4(wp[(4*q+0)*G4], wp[(4*q+1)*G4], \
                                              wp[(4*q+2)*G4], wp[(4*q+3)*G4]);
#define FMAQ(q, a) { float4 h4 = hp[q]; \
    a = fmaf(h4.x, w##q.x, a); a = fmaf(h4.y, w##q.y, a); \
    a = fmaf(h4.z, w##q.z, a); a = fmaf(h4.w, w##q.w, a); }

__global__ __launch_bounds__(512, 1) void lstm_kernel(const float* __restrict__ xw,
                                                      const float* __restrict__ W_hh,
                                                      const float* __restrict__ W_fc,
                                                      const float* __restrict__ b_fc,
                                                      float* __restrict__ out) {
  __shared__ float h_sh[HH];
  __shared__ float act[G4];
  int b = blockIdx.x, j = threadIdx.x;
  const float* wp = W_hh + j;
  ALL_Q(DECLW)  // 128 weights of column j in 32 named float4 SSA values
  float c = 0.f;  // cell state, valid for j < HH
  if (j < HH) h_sh[j] = 0.f;
  bool is_g = (j >> 7) == 2;  // gate order i,f,g,o
  const float* xp = xw + (size_t)b * TT * G4 + j;
  __syncthreads();
  float xv = *xp;  // x for t=0
  const float4* hp = (const float4*)h_sh;
#pragma unroll 1
  for (int t = 0; t < TT; ++t) {
    xp += G4;
    float xn = *xp;  // prefetch x for t+1; stays in flight across raw barriers
    float a0 = xv, a1 = 0.f, a2 = 0.f, a3 = 0.f;
    ALL_Q(FMAQ)   // 128 FMAs, broadcast LDS h reads (conflict-free), 4 chains
    float accs = (a0 + a1) + (a2 + a3);
    float a = is_g ? tanh_fast(accs) : sigm(accs);
    act[j] = a;
    LDS_BARRIER();  // act visible + all h_sh reads done
    if (j < HH) {
      float ig = act[j], fg = act[HH + j], gg = act[2 * HH + j], og = act[3 * HH + j];
      c = fmaf(fg, c, ig * gg);
      h_sh[j] = og * tanh_fast(c);
    }
    LDS_BARRIER();  // h_sh ready for next step
    xv = xn;
  }
  // classifier: out[b, cls] = h_T . W_fc[:, cls] + b_fc[cls]
  if (j < 4) {
    float acc = b_fc[j];
#pragma unroll 8
    for (int k = 0; k < HH; ++k) acc = fmaf(h_sh[k], W_fc[k * 4 + j], acc);
    out[b * 4 + j] = acc;
  }
}

extern "C" void kernel_launch(void* const* d_in, const int* in_sizes, int n_in,
                              void* d_out, int out_size, void* d_ws, size_t ws_size,
                              hipStream_t stream) {
  const float* x_seq   = (const float*)d_in[0];
  const int*   ei      = (const int*)d_in[1];
  const float* w_gat   = (const float*)d_in[2];
  const float* att_src = (const float*)d_in[3];
  const float* att_dst = (const float*)d_in[4];
  const float* b_gat   = (const float*)d_in[5];
  const float* W_ih    = (const float*)d_in[6];
  const float* W_hh    = (const float*)d_in[7];
  const float* b_ih    = (const float*)d_in[8];
  const float* b_hh    = (const float*)d_in[9];
  const float* W_fc    = (const float*)d_in[10];
  const float* b_fc    = (const float*)d_in[11];

  float* ws = (float*)d_ws;
  float* xw       = ws;                          // 16384*512 = 8388608 f
  float* W_eff    = xw + (size_t)NPOS * G4;      // 32*512    = 16384 f
  float* bias_eff = W_eff + NN * G4;             // 512 f
  float* scal     = bias_eff + G4;               // 2 f
  float* biasp    = scal + 2;                    // 32*512 f

  prep_kernel<<<NN, G4, 0, stream>>>(w_gat, b_gat, W_ih, W_eff, biasp);
  prep2_kernel<<<1, G4, 0, stream>>>(biasp, b_ih, b_hh, w_gat, att_src, att_dst, bias_eff, scal);
  gatxw_kernel<<<NPOS / 8, 256, 0, stream>>>(x_seq, ei, scal, W_eff, bias_eff, xw);
  lstm_kernel<<<BB, G4, 0, stream>>>(xw, W_hh, W_fc, b_fc, (float*)d_out);
}